// Round 2
// baseline (81.894 us; speedup 1.0000x reference)
//
#include <hip/hip_runtime.h>

#define NPIX 2304              // 48*48
#define BB   2
#define CF   32
#define NP   3                 // classes after [:,1:]
#define TILE 64
#define NT   (NPIX / TILE)     // 36 tiles per axis
#define NTRI (NT * (NT + 1) / 2)  // 666 upper-tri tiles
#define KP   2.885390081777927f   // 4/ln(4)

__device__ __forceinline__ float frcp(float x) { return __builtin_amdgcn_rcpf(x); }

// workspace param rows per (b,n): 0 mu, 1 si2, 2 h=0.5/si2, 3 rn=rsqrt(norm2),
// 4..6 u_k = q*E, 7..9 s_k = q*q. Layout: par[(b*10 + row)*NPIX + n].

__global__ void precompute_kernel(const float* __restrict__ f,
                                  const float* __restrict__ p,
                                  float* __restrict__ par,
                                  double* __restrict__ acc) {
    int idx = blockIdx.x * blockDim.x + threadIdx.x;
    if (idx == 0) *acc = 0.0;   // ws is re-poisoned before every launch
    if (idx >= BB * NPIX) return;
    int b = idx / NPIX, n = idx % NPIX;

    const float* fb = f + (size_t)b * CF * NPIX + n;
    float s1 = 0.f, s2 = 0.f;
#pragma unroll
    for (int c = 0; c < CF; ++c) {
        float v = fb[(size_t)c * NPIX];
        s1 += v;
        s2 = fmaf(v, v, s2);
    }
    float mu  = s1 * (1.0f / CF);
    float var = (s2 - s1 * s1 * (1.0f / CF)) * (1.0f / (CF - 1));

    float* pb = par + ((size_t)b * 10) * NPIX + n;
    pb[0 * NPIX] = mu;
    pb[1 * NPIX] = var;
    pb[2 * NPIX] = 0.5f / var;
    pb[3 * NPIX] = rsqrtf(s2);

    // softmax over the 4 classes, keep classes 1..3 (full-precision here)
    const float* pp = p + (size_t)b * 4 * NPIX + n;
    float x0 = pp[0], x1 = pp[NPIX], x2 = pp[2 * NPIX], x3 = pp[3 * NPIX];
    float m  = fmaxf(fmaxf(x0, x1), fmaxf(x2, x3));
    float e0 = expf(x0 - m), e1 = expf(x1 - m), e2 = expf(x2 - m), e3 = expf(x3 - m);
    float inv = 1.0f / (e0 + e1 + e2 + e3);
    float q[3] = { e1 * inv, e2 * inv, e3 * inv };
#pragma unroll
    for (int k = 0; k < 3; ++k) {
        float qq = q[k];
        float E  = 1.0f + KP * qq * logf(qq);
        pb[(4 + k) * NPIX] = qq * E;   // u
        pb[(7 + k) * NPIX] = qq * qq;  // s
    }
}

__global__ __launch_bounds__(256) void pair_kernel(const float* __restrict__ f,
                                                   const float* __restrict__ par,
                                                   double* __restrict__ acc) {
    __shared__ float sFi[CF][TILE];
    __shared__ float sFj[CF][TILE];
    __shared__ float sPi[10][TILE];
    __shared__ float sPj[10][TILE];

    const int b = blockIdx.y;
    // triangular decode: tile (ti,tj), tj >= ti
    int rem = blockIdx.x, ti = 0;
    while (rem >= NT - ti) { rem -= NT - ti; ++ti; }   // uniform scalar loop, <=36 iters
    const int tj = ti + rem;
    const int i0 = ti * TILE, j0 = tj * TILE;
    const int tid = threadIdx.x;

    // stage tiles (coalesced along n)
    {
        const float* fb = f + (size_t)b * CF * NPIX;
        int col = tid & 63, c0 = tid >> 6;
        for (int c = c0; c < CF; c += 4) {
            sFi[c][col] = fb[(size_t)c * NPIX + i0 + col];
            sFj[c][col] = fb[(size_t)c * NPIX + j0 + col];
        }
        const float* pb = par + (size_t)b * 10 * NPIX;
        for (int idx = tid; idx < 10 * TILE; idx += 256) {
            int r = idx >> 6, cc = idx & 63;
            sPi[r][cc] = pb[(size_t)r * NPIX + i0 + cc];
            sPj[r][cc] = pb[(size_t)r * NPIX + j0 + cc];
        }
    }
    __syncthreads();

    const int tx = tid & 15;   // j direction
    const int ty = tid >> 4;   // i direction

    float accv[4][4];
#pragma unroll
    for (int m = 0; m < 4; ++m)
#pragma unroll
        for (int n = 0; n < 4; ++n) accv[m][n] = 0.f;

#pragma unroll 8
    for (int c = 0; c < CF; ++c) {
        const float4 a4 = *(const float4*)&sFi[c][ty * 4];
        const float4 b4 = *(const float4*)&sFj[c][tx * 4];
        float ai[4] = { a4.x, a4.y, a4.z, a4.w };
        float bj[4] = { b4.x, b4.y, b4.z, b4.w };
#pragma unroll
        for (int m = 0; m < 4; ++m)
#pragma unroll
            for (int n = 0; n < 4; ++n)
                accv[m][n] = fmaf(ai[m], bj[n], accv[m][n]);
    }

    // hoist j-side params to registers (constant over the m loop)
    float pj[10][4];
#pragma unroll
    for (int r = 0; r < 10; ++r)
#pragma unroll
        for (int n = 0; n < 4; ++n) pj[r][n] = sPj[r][tx * 4 + n];

    float fsum = 0.f;
#pragma unroll
    for (int m = 0; m < 4; ++m) {
        const int ii = ty * 4 + m;
        const float mu_i = sPi[0][ii], si2_i = sPi[1][ii];
        const float h_i  = sPi[2][ii], rn_i  = sPi[3][ii];
        const float u_i0 = sPi[4][ii], u_i1 = sPi[5][ii], u_i2 = sPi[6][ii];
        const float s_i0 = sPi[7][ii], s_i1 = sPi[8][ii], s_i2 = sPi[9][ii];
#pragma unroll
        for (int n = 0; n < 4; ++n) {
            const float d    = mu_i - pj[0][n];
            const float dmu2 = d * d;
            // log_ratio == log(x)+log(1/x) == 0; omitted
            const float KL   = 0.5f * ((si2_i + dmu2) * pj[2][n] + (pj[1][n] + dmu2) * h_i - 1.0f);
            const float cosv = accv[m][n] * rn_i * pj[3][n];
            const float dist = (KL + 2.0f - 2.0f * cosv) * (1.0f / 3.0f);
            const float wm   = __expf(-4.0f * dist * dist);  // theta=0.5 -> 1/theta^2=4
            const float g = 2.0f * ( u_i0 * pj[4][n] * frcp(s_i0 + pj[7][n])
                                   + u_i1 * pj[5][n] * frcp(s_i1 + pj[8][n])
                                   + u_i2 * pj[6][n] * frcp(s_i2 + pj[9][n]) );
            fsum = fmaf(wm, g, fsum);
        }
    }

    // block reduction in double, then one atomic per block
    double sum = (double)fsum;
    for (int off = 32; off; off >>= 1) sum += __shfl_down(sum, off);
    __shared__ double wsumd[4];
    const int lane = tid & 63, wid = tid >> 6;
    if (lane == 0) wsumd[wid] = sum;
    __syncthreads();
    if (tid == 0) {
        const double wgt = (ti == tj) ? 1.0 : 2.0;  // symmetry
        double t = (wsumd[0] + wsumd[1]) + (wsumd[2] + wsumd[3]);
        atomicAdd(acc, t * wgt);
    }
}

__global__ void finalize_kernel(const double* __restrict__ acc, float* __restrict__ out) {
    // result = 1 - total / (B * P * N * N)
    out[0] = (float)(1.0 - acc[0] / ((double)BB * NP * (double)NPIX * (double)NPIX));
}

extern "C" void kernel_launch(void* const* d_in, const int* in_sizes, int n_in,
                              void* d_out, int out_size, void* d_ws, size_t ws_size,
                              hipStream_t stream) {
    const float* f = (const float*)d_in[0];
    const float* p = (const float*)d_in[1];
    float*  par = (float*)d_ws;
    double* acc = (double*)((char*)d_ws + (size_t)10 * BB * NPIX * sizeof(float)); // 92160 B, 8-aligned
    float*  out = (float*)d_out;

    precompute_kernel<<<(BB * NPIX + 255) / 256, 256, 0, stream>>>(f, p, par, acc);
    dim3 grid(NTRI, BB);
    pair_kernel<<<grid, 256, 0, stream>>>(f, par, acc);
    finalize_kernel<<<1, 1, 0, stream>>>(acc, out);
}

// Round 3
// 71.063 us; speedup vs baseline: 1.1524x; 1.1524x over previous
//
#include <hip/hip_runtime.h>

#define NPIX 2304              // 48*48
#define BB   2
#define CF   32
#define NP   3                 // classes after [:,1:]
#define TILE 64
#define NT   (NPIX / TILE)        // 36 tiles per axis
#define NTRI (NT * (NT + 1) / 2)  // 666 upper-tri tiles
#define KP   2.885390081777927f   // 4/ln(4)

__device__ __forceinline__ float frcp(float x) { return __builtin_amdgcn_rcpf(x); }

// Fused: stages f tiles, computes per-pixel params in-block (mu, si2, h, rn,
// u_k=q*E, s_k=q*q), does the 64x64 pair tile, writes one double partial per
// block into d_ws (poison gets overwritten; no zeroing, no atomics).
__global__ __launch_bounds__(256) void pair_kernel(const float* __restrict__ f,
                                                   const float* __restrict__ p,
                                                   double* __restrict__ partial) {
    __shared__ float sFi[CF][TILE];
    __shared__ float sFj[CF][TILE];
    __shared__ float sPi[10][TILE];
    __shared__ float sPj[10][TILE];

    const int b = blockIdx.y;
    // triangular decode: tile (ti,tj), tj >= ti  (uniform scalar loop, <=36 iters)
    int rem = blockIdx.x, ti = 0;
    while (rem >= NT - ti) { rem -= NT - ti; ++ti; }
    const int tj = ti + rem;
    const int i0 = ti * TILE, j0 = tj * TILE;
    const int tid = threadIdx.x;

    // ---- stage f tiles (coalesced along n) ----
    {
        const float* fb = f + (size_t)b * CF * NPIX;
        int col = tid & 63, c0 = tid >> 6;
        for (int c = c0; c < CF; c += 4) {
            sFi[c][col] = fb[(size_t)c * NPIX + i0 + col];
            sFj[c][col] = fb[(size_t)c * NPIX + j0 + col];
        }
    }
    __syncthreads();

    // ---- in-block per-pixel params: threads 0..63 -> i side, 64..127 -> j side ----
    if (tid < 128) {
        const int side = tid >> 6;           // 0 = i, 1 = j
        const int col  = tid & 63;
        const float (*sF)[TILE] = side ? sFj : sFi;
        float (*sP)[TILE]       = side ? sPj : sPi;
        const int base = (side ? j0 : i0) + col;

        float s1 = 0.f, s2 = 0.f;
#pragma unroll
        for (int c = 0; c < CF; ++c) {
            float v = sF[c][col];
            s1 += v;
            s2 = fmaf(v, v, s2);
        }
        float mu  = s1 * (1.0f / CF);
        float var = (s2 - s1 * s1 * (1.0f / CF)) * (1.0f / (CF - 1));
        sP[0][col] = mu;
        sP[1][col] = var;
        sP[2][col] = 0.5f / var;
        sP[3][col] = rsqrtf(s2);

        // softmax over the 4 classes (full precision), keep 1..3
        const float* pp = p + (size_t)b * 4 * NPIX + base;
        float x0 = pp[0], x1 = pp[NPIX], x2 = pp[2 * NPIX], x3 = pp[3 * NPIX];
        float m  = fmaxf(fmaxf(x0, x1), fmaxf(x2, x3));
        float e0 = expf(x0 - m), e1 = expf(x1 - m), e2 = expf(x2 - m), e3 = expf(x3 - m);
        float inv = 1.0f / (e0 + e1 + e2 + e3);
        float q[3] = { e1 * inv, e2 * inv, e3 * inv };
#pragma unroll
        for (int k = 0; k < 3; ++k) {
            float qq = q[k];
            float E  = 1.0f + KP * qq * logf(qq);
            sP[4 + k][col] = qq * E;   // u
            sP[7 + k][col] = qq * qq;  // s
        }
    }
    __syncthreads();

    const int tx = tid & 15;   // j direction
    const int ty = tid >> 4;   // i direction

    float accv[4][4];
#pragma unroll
    for (int m = 0; m < 4; ++m)
#pragma unroll
        for (int n = 0; n < 4; ++n) accv[m][n] = 0.f;

#pragma unroll 8
    for (int c = 0; c < CF; ++c) {
        const float4 a4 = *(const float4*)&sFi[c][ty * 4];
        const float4 b4 = *(const float4*)&sFj[c][tx * 4];
        float ai[4] = { a4.x, a4.y, a4.z, a4.w };
        float bj[4] = { b4.x, b4.y, b4.z, b4.w };
#pragma unroll
        for (int m = 0; m < 4; ++m)
#pragma unroll
            for (int n = 0; n < 4; ++n)
                accv[m][n] = fmaf(ai[m], bj[n], accv[m][n]);
    }

    // hoist j-side params to registers (constant over the m loop)
    float pj[10][4];
#pragma unroll
    for (int r = 0; r < 10; ++r)
#pragma unroll
        for (int n = 0; n < 4; ++n) pj[r][n] = sPj[r][tx * 4 + n];

    float fsum = 0.f;
#pragma unroll
    for (int m = 0; m < 4; ++m) {
        const int ii = ty * 4 + m;
        const float mu_i = sPi[0][ii], si2_i = sPi[1][ii];
        const float h_i  = sPi[2][ii], rn_i  = sPi[3][ii];
        const float u_i0 = sPi[4][ii], u_i1 = sPi[5][ii], u_i2 = sPi[6][ii];
        const float s_i0 = sPi[7][ii], s_i1 = sPi[8][ii], s_i2 = sPi[9][ii];
#pragma unroll
        for (int n = 0; n < 4; ++n) {
            const float d    = mu_i - pj[0][n];
            const float dmu2 = d * d;
            // log_ratio == log(x)+log(1/x) == 0; omitted
            const float KL   = 0.5f * ((si2_i + dmu2) * pj[2][n] + (pj[1][n] + dmu2) * h_i - 1.0f);
            const float cosv = accv[m][n] * rn_i * pj[3][n];
            const float dist = (KL + 2.0f - 2.0f * cosv) * (1.0f / 3.0f);
            const float wm   = __expf(-4.0f * dist * dist);  // theta=0.5 -> 1/theta^2=4
            const float g = 2.0f * ( u_i0 * pj[4][n] * frcp(s_i0 + pj[7][n])
                                   + u_i1 * pj[5][n] * frcp(s_i1 + pj[8][n])
                                   + u_i2 * pj[6][n] * frcp(s_i2 + pj[9][n]) );
            fsum = fmaf(wm, g, fsum);
        }
    }

    // block reduction in double, one plain store per block (no atomics)
    double sum = (double)fsum;
    for (int off = 32; off; off >>= 1) sum += __shfl_down(sum, off);
    __shared__ double wsumd[4];
    const int lane = tid & 63, wid = tid >> 6;
    if (lane == 0) wsumd[wid] = sum;
    __syncthreads();
    if (tid == 0) {
        const double wgt = (ti == tj) ? 1.0 : 2.0;  // symmetry
        partial[(size_t)b * NTRI + blockIdx.x] =
            ((wsumd[0] + wsumd[1]) + (wsumd[2] + wsumd[3])) * wgt;
    }
}

__global__ __launch_bounds__(256) void finalize_kernel(const double* __restrict__ partial,
                                                       float* __restrict__ out) {
    double s = 0.0;
    for (int i = threadIdx.x; i < BB * NTRI; i += 256) s += partial[i];
    for (int off = 32; off; off >>= 1) s += __shfl_down(s, off);
    __shared__ double wsumd[4];
    const int lane = threadIdx.x & 63, wid = threadIdx.x >> 6;
    if (lane == 0) wsumd[wid] = s;
    __syncthreads();
    if (threadIdx.x == 0) {
        double total = (wsumd[0] + wsumd[1]) + (wsumd[2] + wsumd[3]);
        out[0] = (float)(1.0 - total / ((double)BB * NP * (double)NPIX * (double)NPIX));
    }
}

extern "C" void kernel_launch(void* const* d_in, const int* in_sizes, int n_in,
                              void* d_out, int out_size, void* d_ws, size_t ws_size,
                              hipStream_t stream) {
    const float* f = (const float*)d_in[0];
    const float* p = (const float*)d_in[1];
    double* partial = (double*)d_ws;           // NTRI*BB doubles, all overwritten
    float*  out     = (float*)d_out;

    dim3 grid(NTRI, BB);
    pair_kernel<<<grid, 256, 0, stream>>>(f, p, partial);
    finalize_kernel<<<1, 256, 0, stream>>>(partial, out);
}